// Round 10
// baseline (55.188 us; speedup 1.0000x reference)
//
#include <hip/hip_runtime.h>
#include <hip/hip_bf16.h>
#include <stdint.h>

#define H 512
#define W 512
#define HW (H * W)
#define SR 8              // rows per k_sal wave
#define NSTRIP (H / SR)   // 64 strips per image

__device__ __forceinline__ int refl(int i, int n) {
    // BORDER_REFLECT_101: -1 -> 1, n -> n-2
    return i < 0 ? -i : (i >= n ? 2 * n - 2 - i : i);
}

// Load one image row (reflected y), compute QUANTIZED gray (float of uint8) for
// this lane's 8 px, and build the 10-col halo-extended window via shuffles.
__device__ __forceinline__ void graywin(const float4* __restrict__ p4, int y, int lane,
                                        float* __restrict__ h) {
    int o = refl(y, H) * (W / 4) + lane * 2;
    float4 r0 = p4[o],                  r1 = p4[o + 1];
    float4 g0 = p4[o + HW / 4],         g1 = p4[o + 1 + HW / 4];
    float4 b0 = p4[o + 2 * (HW / 4)],   b1 = p4[o + 1 + 2 * (HW / 4)];
    float g[8];
    g[0] = (float)(uint8_t)((0.2989f * r0.x + 0.587f * g0.x + 0.114f * b0.x) * 255.0f);
    g[1] = (float)(uint8_t)((0.2989f * r0.y + 0.587f * g0.y + 0.114f * b0.y) * 255.0f);
    g[2] = (float)(uint8_t)((0.2989f * r0.z + 0.587f * g0.z + 0.114f * b0.z) * 255.0f);
    g[3] = (float)(uint8_t)((0.2989f * r0.w + 0.587f * g0.w + 0.114f * b0.w) * 255.0f);
    g[4] = (float)(uint8_t)((0.2989f * r1.x + 0.587f * g1.x + 0.114f * b1.x) * 255.0f);
    g[5] = (float)(uint8_t)((0.2989f * r1.y + 0.587f * g1.y + 0.114f * b1.y) * 255.0f);
    g[6] = (float)(uint8_t)((0.2989f * r1.z + 0.587f * g1.z + 0.114f * b1.z) * 255.0f);
    g[7] = (float)(uint8_t)((0.2989f * r1.w + 0.587f * g1.w + 0.114f * b1.w) * 255.0f);
    #pragma unroll
    for (int j = 0; j < 8; ++j) h[j + 1] = g[j];
    float up = __shfl_up(g[7], 1);     // lane-1's x = lane*8-1
    float dn = __shfl_down(g[0], 1);   // lane+1's x = lane*8+8
    h[0] = (lane == 0)  ? g[1] : up;   // x=-1  -> x=1
    h[9] = (lane == 63) ? g[6] : dn;   // x=512 -> x=510
}

// ---------------- K1: gray + sobel + per-strip min/max + q emit ----------------
// ONE WAVE per 8-row strip per source. No LDS, no __syncthreads: waves are fully
// independent and self-stagger, keeping the memory pipe full (lockstep rounds
// were the 2.85 TB/s ceiling in the block-tiled version).
__global__ __launch_bounds__(64) void k_sal(const float* __restrict__ vis,
                                            const float* __restrict__ ir,
                                            uint8_t* __restrict__ qvis,
                                            uint8_t* __restrict__ qir,
                                            float* __restrict__ pm, int B) {
    int lane = threadIdx.x;              // 64-thread block = one wave
    int gwave = blockIdx.x;              // [0, 2*B*NSTRIP)
    int per_src = B * NSTRIP;            // 1024
    int src = gwave >= per_src;
    int rem = src ? gwave - per_src : gwave;
    int b     = rem >> 6;                // 64 strips per image
    int strip = rem & 63;
    int y0 = strip * SR;

    const float4* p4 = (const float4*)((src ? ir : vis) + (size_t)b * 3 * HW);
    uint8_t* q = (src ? qir : qvis) + (size_t)b * HW;

    float rw[3][10];
    graywin(p4, y0 - 1, lane, rw[0]);
    graywin(p4, y0,     lane, rw[1]);

    float mn = INFINITY, mx = 0.0f;
    #pragma unroll
    for (int r = 0; r < SR; ++r) {
        float* hm = rw[r % 3];           // row y0+r-1   (static after unroll)
        float* h0 = rw[(r + 1) % 3];     // row y0+r
        float* hp = rw[(r + 2) % 3];     // row y0+r+1
        graywin(p4, y0 + r + 1, lane, hp);

        // q writeback for center row (values are exact small ints in float)
        uint32_t u0 = ((uint32_t)h0[1]) | ((uint32_t)h0[2] << 8) |
                      ((uint32_t)h0[3] << 16) | ((uint32_t)h0[4] << 24);
        uint32_t u1 = ((uint32_t)h0[5]) | ((uint32_t)h0[6] << 8) |
                      ((uint32_t)h0[7] << 16) | ((uint32_t)h0[8] << 24);
        uint2 qw; qw.x = u0; qw.y = u1;
        *(uint2*)(q + (size_t)(y0 + r) * W + lane * 8) = qw;

        float sx[10], sy[10];
        #pragma unroll
        for (int j = 0; j < 10; ++j) {
            sx[j] = hm[j] + 2.0f * h0[j] + hp[j];
            sy[j] = hp[j] - hm[j];
        }
        #pragma unroll
        for (int k = 0; k < 8; ++k) {
            float gx = sx[k + 2] - sx[k];
            float gy = sy[k] + 2.0f * sy[k + 1] + sy[k + 2];
            float m = sqrtf(gx * gx + gy * gy);
            mn = fminf(mn, m);
            mx = fmaxf(mx, m);
        }
    }

    // wave reduce + plain store (no atomics)
    #pragma unroll
    for (int o = 32; o > 0; o >>= 1) {
        mn = fminf(mn, __shfl_down(mn, o));
        mx = fmaxf(mx, __shfl_down(mx, o));
    }
    if (lane == 0) {
        float* o = pm + ((size_t)(src * B + b) * NSTRIP + strip) * 2;
        o[0] = mn;
        o[1] = mx;
    }
}

// Extract this lane's 10 stencil columns from an 8-byte row segment via shuffles.
__device__ __forceinline__ void row_cols(uint2 v, int lane, float* __restrict__ c) {
    uint32_t lx = __shfl_up(v.y, 1);
    uint32_t rx = __shfl_down(v.x, 1);
    uint32_t lb = (lane == 0)  ? ((v.x >> 8) & 0xffu)  : (lx >> 24);
    uint32_t rb = (lane == 63) ? ((v.y >> 16) & 0xffu) : (rx & 0xffu);
    c[0] = (float)lb;
    c[1] = (float)(v.x & 0xffu);
    c[2] = (float)((v.x >> 8) & 0xffu);
    c[3] = (float)((v.x >> 16) & 0xffu);
    c[4] = (float)(v.x >> 24);
    c[5] = (float)(v.y & 0xffu);
    c[6] = (float)((v.y >> 8) & 0xffu);
    c[7] = (float)((v.y >> 16) & 0xffu);
    c[8] = (float)(v.y >> 24);
    c[9] = (float)rb;
}

__device__ __forceinline__ void sobel_row8(const uint8_t* __restrict__ q, int y, int lane,
                                           float* __restrict__ mag) {
    const uint2* rm = (const uint2*)(q + (size_t)refl(y - 1, H) * W);
    const uint2* r0 = (const uint2*)(q + (size_t)y * W);
    const uint2* rp = (const uint2*)(q + (size_t)refl(y + 1, H) * W);
    uint2 vm = rm[lane], v0 = r0[lane], vp = rp[lane];
    float c0[10], c1[10], c2[10];
    row_cols(vm, lane, c0);
    row_cols(v0, lane, c1);
    row_cols(vp, lane, c2);
    float sx[10], sy[10];
    #pragma unroll
    for (int j = 0; j < 10; ++j) {
        sx[j] = c0[j] + 2.0f * c1[j] + c2[j];
        sy[j] = c2[j] - c0[j];
    }
    #pragma unroll
    for (int k = 0; k < 8; ++k) {
        float gx = sx[k + 2] - sx[k];
        float gy = sy[k] + 2.0f * sy[k + 1] + sy[k + 2];
        mag[k] = sqrtf(gx * gx + gy * gy);
    }
}

// ---------------- K2: minmax finalize + weighted blend + |diff| partial sums ----------------
// block = 4 waves; prologue: wave w shuffle-reduces one of {mn_v,mx_v,mn_i,mx_i}
// from the 64 per-strip partials; then each wave handles rows y0+w and y0+w+4.
__global__ __launch_bounds__(256) void k_loss(const float* __restrict__ vis,
                                              const float* __restrict__ ir,
                                              const float* __restrict__ fus,
                                              const uint8_t* __restrict__ qvis,
                                              const uint8_t* __restrict__ qir,
                                              const float* __restrict__ pm,
                                              float* __restrict__ partial, int B) {
    int w = threadIdx.x >> 6, lane = threadIdx.x & 63;
    int b = blockIdx.x >> 6;
    int y0 = (blockIdx.x & 63) * 8;

    __shared__ float sred[4];
    {
        int src = w >> 1, qsel = w & 1;
        float v = pm[((size_t)(src * B + b) * NSTRIP + lane) * 2 + qsel];
        if (qsel == 0) {
            #pragma unroll
            for (int o = 32; o > 0; o >>= 1) v = fminf(v, __shfl_down(v, o));
        } else {
            #pragma unroll
            for (int o = 32; o > 0; o >>= 1) v = fmaxf(v, __shfl_down(v, o));
        }
        if (lane == 0) sred[w] = v;
    }
    __syncthreads();
    float mn_v = sred[0], mx_v = sred[1], mn_i = sred[2], mx_i = sred[3];
    float inv_v = 1.0f / fmaxf(mx_v - mn_v, 1e-8f);
    float inv_i = 1.0f / fmaxf(mx_i - mn_i, 1e-8f);

    float acc = 0.0f;
    #pragma unroll
    for (int rr = 0; rr < 2; ++rr) {
        int y = y0 + w + rr * 4;
        float mv[8], mi[8];
        sobel_row8(qvis + (size_t)b * HW, y, lane, mv);
        sobel_row8(qir  + (size_t)b * HW, y, lane, mi);

        float wv[8], wi[8];
        #pragma unroll
        for (int k = 0; k < 8; ++k) {
            float sv = (mv[k] - mn_v) * inv_v;
            float si = (mi[k] - mn_i) * inv_i;
            float den = sv + si + 1e-8f;
            float rden = 1.0f / den;
            wv[k] = sv * rden;
            wi[k] = si * rden;
        }

        int i = y * W + lane * 8;
        #pragma unroll
        for (int ch = 0; ch < 3; ++ch) {
            size_t e4 = ((((size_t)b * 3 + ch) * HW) + i) >> 2;
            const float4* v4 = (const float4*)vis;
            const float4* r4 = (const float4*)ir;
            const float4* f4 = (const float4*)fus;
            float4 va = v4[e4], vb = v4[e4 + 1];
            float4 ra = r4[e4], rb = r4[e4 + 1];
            float4 fa = f4[e4], fb = f4[e4 + 1];
            acc += fabsf(wv[0] * va.x + wi[0] * ra.x - fa.x);
            acc += fabsf(wv[1] * va.y + wi[1] * ra.y - fa.y);
            acc += fabsf(wv[2] * va.z + wi[2] * ra.z - fa.z);
            acc += fabsf(wv[3] * va.w + wi[3] * ra.w - fa.w);
            acc += fabsf(wv[4] * vb.x + wi[4] * rb.x - fb.x);
            acc += fabsf(wv[5] * vb.y + wi[5] * rb.y - fb.y);
            acc += fabsf(wv[6] * vb.z + wi[6] * rb.z - fb.z);
            acc += fabsf(wv[7] * vb.w + wi[7] * rb.w - fb.w);
        }
    }

    #pragma unroll
    for (int o = 32; o > 0; o >>= 1) acc += __shfl_down(acc, o);
    __shared__ float ssum[4];
    if (lane == 0) ssum[w] = acc;
    __syncthreads();
    if (threadIdx.x == 0) partial[blockIdx.x] = ssum[0] + ssum[1] + ssum[2] + ssum[3];
}

// ---------------- K3: final reduce ----------------
__global__ void k_final(const float* __restrict__ partial, int n, float* __restrict__ out,
                        long long N) {
    double s = 0.0;
    for (int i = threadIdx.x; i < n; i += 256) s += (double)partial[i];
    __shared__ double sm[256];
    sm[threadIdx.x] = s;
    __syncthreads();
    for (int k = 128; k > 0; k >>= 1) {
        if (threadIdx.x < k) sm[threadIdx.x] += sm[threadIdx.x + k];
        __syncthreads();
    }
    if (threadIdx.x == 0) out[0] = (float)(sm[0] / (double)N);
}

extern "C" void kernel_launch(void* const* d_in, const int* in_sizes, int n_in,
                              void* d_out, int out_size, void* d_ws, size_t ws_size,
                              hipStream_t stream) {
    const float* vis = (const float*)d_in[0];
    const float* ir  = (const float*)d_in[1];
    const float* fus = (const float*)d_in[2];
    int B = in_sizes[0] / (3 * HW);  // 16

    uint8_t* qvis = (uint8_t*)d_ws;
    uint8_t* qir  = qvis + (size_t)B * HW;
    float* pm      = (float*)(qir + (size_t)B * HW);       // 2*B*64*2 floats
    float* partial = pm + (size_t)2 * B * NSTRIP * 2;      // 1024 floats
    float* out = (float*)d_out;

    int nblk_sal = 2 * B * NSTRIP;   // 2048 one-wave blocks (one 8-row strip each)
    k_sal<<<nblk_sal, 64, 0, stream>>>(vis, ir, qvis, qir, pm, B);

    int nblk_loss = B * (H / 8);     // 1024 blocks
    k_loss<<<nblk_loss, 256, 0, stream>>>(vis, ir, fus, qvis, qir, pm, partial, B);

    k_final<<<1, 256, 0, stream>>>(partial, nblk_loss, out, (long long)B * 3 * HW);
}